// Round 2
// baseline (1100.721 us; speedup 1.0000x reference)
//
#include <hip/hip_runtime.h>
#include <math.h>

#define DIN    128
#define KN     32
#define TSIZE  2048     // sigmoid-sum table resolution on [0,1]
#define NBLK   2048     // grid blocks (x4 waves = 8192 waves, ~6 n each)

// ---------------------------------------------------------------------------
// Kernel 1 (tiny): ws[0..127]=u=W2@W4, ws[128..255]=v=W1@W4,
//                  ws[256..256+2048]=table[i]=sum_e sigmoid((i/2048)*W3[e])*W4[e]
// ---------------------------------------------------------------------------
__global__ void precompute(const float* __restrict__ W1,
                           const float* __restrict__ W2,
                           const float* __restrict__ W3,
                           const float* __restrict__ W4,
                           float* __restrict__ ws) {
    int t = blockIdx.x * 256 + threadIdx.x;
    if (t < 256) {
        const float* Wm = (t < DIN) ? W2 : W1;
        int d = t & (DIN - 1);
        const float* row = Wm + d * DIN;
        float acc = 0.f;
        for (int e = 0; e < DIN; ++e) acc += row[e] * W4[e];
        ws[t] = acc;
    } else if (t < 256 + TSIZE + 1) {
        int i = t - 256;
        float x = (float)i * (1.0f / (float)TSIZE);
        float acc = 0.f;
        for (int e = 0; e < DIN; ++e) {
            float z = x * W3[e];
            float s = 1.0f / (1.0f + expf(-z));
            acc += s * W4[e];
        }
        ws[256 + i] = acc;
    }
}

__device__ __forceinline__ float dot4(float4 a, float4 b) {
    return a.x * b.x + a.y * b.y + a.z * b.z + a.w * b.w;
}

// ---------------------------------------------------------------------------
// Kernel 2: one WAVE per n, grid-stride. No __syncthreads in the n-loop.
// Lane (kq=l>>3, dq=l&7) holds neigh[k = kq*4+i][d = c*32+dq*4+j] in regs.
// ---------------------------------------------------------------------------
__global__ __launch_bounds__(256) void attn_fast(
    const float* __restrict__ self_vecs,   // [N,128]
    const float* __restrict__ neigh_vecs,  // [N,32,128]
    const float* __restrict__ dt,          // [N,32]
    const float* __restrict__ b4,          // [1]
    const float* __restrict__ ws,          // u[128] v[128] table[2049]
    float* __restrict__ out,               // [N,128]
    float* __restrict__ score_out,         // [N,32]
    int N)
{
    __shared__ float tab[TSIZE + 1];
    for (int i = threadIdx.x; i < TSIZE + 1; i += 256) tab[i] = ws[256 + i];

    const int l  = threadIdx.x & 63;
    const int w  = threadIdx.x >> 6;
    const int dq = l & 7;
    const int kq = l >> 3;

    // per-lane slices of u and v, resident across the whole n-loop
    float4 u4[4];
    #pragma unroll
    for (int c = 0; c < 4; ++c)
        u4[c] = *(const float4*)(ws + c * 32 + dq * 4);
    const float v0  = ws[DIN + l];
    const float v1  = ws[DIN + 64 + l];
    const float b4v = b4[0];

    __syncthreads();   // table ready (only barrier in the kernel)

    const int wave   = blockIdx.x * 4 + w;
    const int stride = gridDim.x * 4;

    for (int n = wave; n < N; n += stride) {
        // ---- load neigh tile into registers: 16 float4, 8x128B/instr ----
        const float* base = neigh_vecs + (size_t)n * (KN * DIN) + kq * 512 + dq * 4;
        float4 r[4][4];
        #pragma unroll
        for (int i = 0; i < 4; ++i)
            #pragma unroll
            for (int c = 0; c < 4; ++c)
                r[i][c] = *(const float4*)(base + i * DIN + c * 32);

        float dtv[4];
        const float* dtb = dt + (size_t)n * KN + kq * 4;
        #pragma unroll
        for (int i = 0; i < 4; ++i) dtv[i] = dtb[i];

        // ---- q = self[n] . v  (full-wave butterfly) ----
        float q;
        {
            float s0 = self_vecs[(size_t)n * DIN + l];
            float s1 = self_vecs[(size_t)n * DIN + 64 + l];
            q = s0 * v0 + s1 * v1;
            #pragma unroll
            for (int off = 1; off < 64; off <<= 1)
                q += __shfl_xor(q, off, 64);
        }

        // ---- scores: pre[i] for k = kq*4+i ----
        float pre[4];
        #pragma unroll
        for (int i = 0; i < 4; ++i) {
            float p = dot4(r[i][0], u4[0]) + dot4(r[i][1], u4[1])
                    + dot4(r[i][2], u4[2]) + dot4(r[i][3], u4[3]);
            p += __shfl_xor(p, 1, 64);
            p += __shfl_xor(p, 2, 64);
            p += __shfl_xor(p, 4, 64);
            // sigmoid-sum term via table lerp
            float x = dtv[i] * (float)TSIZE;
            x = fmaxf(x, 0.f);
            int idx = (int)x;
            idx = idx < TSIZE ? idx : TSIZE - 1;
            float fr = x - (float)idx;
            float t0 = tab[idx], t1 = tab[idx + 1];
            float tt = t0 + fr * (t1 - t0);
            float sp = q + p + tt + b4v;
            pre[i] = sp > 0.f ? sp : 0.f;
        }

        // ---- softmax over 32 k (cross-group butterflies) ----
        float m = fmaxf(fmaxf(pre[0], pre[1]), fmaxf(pre[2], pre[3]));
        m = fmaxf(m, __shfl_xor(m, 8, 64));
        m = fmaxf(m, __shfl_xor(m, 16, 64));
        m = fmaxf(m, __shfl_xor(m, 32, 64));
        float e0 = __expf(pre[0] - m);
        float e1 = __expf(pre[1] - m);
        float e2 = __expf(pre[2] - m);
        float e3 = __expf(pre[3] - m);
        float s = e0 + e1 + e2 + e3;
        s += __shfl_xor(s, 8, 64);
        s += __shfl_xor(s, 16, 64);
        s += __shfl_xor(s, 32, 64);
        float inv = 1.0f / s;
        float sc0 = e0 * inv, sc1 = e1 * inv, sc2 = e2 * inv, sc3 = e3 * inv;

        if (dq == 0)
            *(float4*)(score_out + (size_t)n * KN + kq * 4) =
                make_float4(sc0, sc1, sc2, sc3);

        // ---- weighted sum: o[c] = sum_i sc_i * r[i][c], reduce over kq ----
        float4 o[4];
        #pragma unroll
        for (int c = 0; c < 4; ++c) {
            o[c].x = sc0 * r[0][c].x + sc1 * r[1][c].x + sc2 * r[2][c].x + sc3 * r[3][c].x;
            o[c].y = sc0 * r[0][c].y + sc1 * r[1][c].y + sc2 * r[2][c].y + sc3 * r[3][c].y;
            o[c].z = sc0 * r[0][c].z + sc1 * r[1][c].z + sc2 * r[2][c].z + sc3 * r[3][c].z;
            o[c].w = sc0 * r[0][c].w + sc1 * r[1][c].w + sc2 * r[2][c].w + sc3 * r[3][c].w;
        }
        #pragma unroll
        for (int c = 0; c < 4; ++c) {
            #pragma unroll
            for (int off = 8; off < 64; off <<= 1) {
                o[c].x += __shfl_xor(o[c].x, off, 64);
                o[c].y += __shfl_xor(o[c].y, off, 64);
                o[c].z += __shfl_xor(o[c].z, off, 64);
                o[c].w += __shfl_xor(o[c].w, off, 64);
            }
        }
        if (kq < 4)
            *(float4*)(out + (size_t)n * DIN + kq * 32 + dq * 4) = o[kq];
    }
}

// ---------------------------------------------------------------------------
extern "C" void kernel_launch(void* const* d_in, const int* in_sizes, int n_in,
                              void* d_out, int out_size, void* d_ws, size_t ws_size,
                              hipStream_t stream) {
    const float* self_vecs = (const float*)d_in[0];
    const float* neigh     = (const float*)d_in[1];
    const float* dtim      = (const float*)d_in[2];
    const float* W1        = (const float*)d_in[3];
    const float* W2        = (const float*)d_in[4];
    const float* W3        = (const float*)d_in[5];
    const float* W4        = (const float*)d_in[6];
    const float* b4        = (const float*)d_in[7];

    const int N = in_sizes[0] / DIN;           // 50000
    float* ws        = (float*)d_ws;           // uv[256] ++ table[2049]
    float* out       = (float*)d_out;          // [N,128]
    float* score_out = out + (size_t)N * DIN;  // [N,32]

    precompute<<<10, 256, 0, stream>>>(W1, W2, W3, W4, ws);
    attn_fast<<<NBLK, 256, 0, stream>>>(self_vecs, neigh, dtim, b4, ws,
                                        out, score_out, N);
}